// Round 1
// baseline (963.199 us; speedup 1.0000x reference)
//
#include <hip/hip_runtime.h>
#include <hip/hip_bf16.h>
#include <stdint.h>

// LiquidEnsembleLayer on MI355X.
// Math: power_ext = pinv(I - D_no_diag) @ 1 reduces to a 16x16 linear solve
// (M is strictly column-diagonally-dominant => invertible; col 16 of the 17x17
//  extended system is e_n, so it block-triangularizes).
// power[i] = (1-eps)*dall[i,i]*p_i + (eps/16)*sum(p)
// y[b] = sum_i power[b,i] * (x[b] @ Wy[i] + by[i])
//      = [power-scaled replicated x] @ [Wy flattened]  (+ bias MFMA step)

using u16 = unsigned short;
typedef __attribute__((ext_vector_type(8))) short short8x;
typedef __attribute__((ext_vector_type(8))) unsigned short ushort8x;
typedef __attribute__((ext_vector_type(4))) float f32x4;

#define EPSI 0.01f

__device__ __forceinline__ u16 f2bf(float f) {
  union { float fl; unsigned int u; } c; c.fl = f;
  unsigned int u = c.u;
  u += 0x7fffu + ((u >> 16) & 1u);   // RNE round to bf16
  return (u16)(u >> 16);
}

__device__ __forceinline__ void gload_lds16(const void* g, void* l) {
  __builtin_amdgcn_global_load_lds(
      (const __attribute__((address_space(1))) unsigned int*)g,
      (__attribute__((address_space(3))) unsigned int*)l, 16, 0, 0);
}

// ---------------------------------------------------------------------------
// Kernel 1: Wy f32 [16][1024][1024] -> bf16, GEMM-K-reordered + swizzled tiles.
// GEMM k-index: kt = kc*16 + ii (kc = chunk of 32 within DIN, ii = citizen).
// Tile layout: Bp[kt*32768 + o*32 + sb*8 + kr], sb = kb ^ ((o>>1)&3)
// (XOR swizzle baked into global layout so global_load_lds copies linearly,
//  and ds_read_b128 B-frag reads land 2-way = free banks).
// ---------------------------------------------------------------------------
__global__ __launch_bounds__(256) void convert_wy_kernel(
    const float* __restrict__ Wy, u16* __restrict__ Bp)
{
  const int kt = blockIdx.x;           // 0..511
  const int ii = kt & 15;
  const int kc = kt >> 4;
  const int o0 = threadIdx.x * 4;      // 4 consecutive output cols per thread
  const float* src = Wy + (size_t)ii * 1048576 + (size_t)(kc * 32) * 1024;
  u16* dst = Bp + (size_t)kt * 32768;

  #pragma unroll
  for (int kb = 0; kb < 4; ++kb) {
    float4 v[8];
    #pragma unroll
    for (int q = 0; q < 8; ++q)
      v[q] = *(const float4*)(src + (size_t)(kb * 8 + q) * 1024 + o0);
    #pragma unroll
    for (int oo = 0; oo < 4; ++oo) {
      const int o = o0 + oo;
      ushort8x pk;
      #pragma unroll
      for (int q = 0; q < 8; ++q) {
        const float* vp = (const float*)&v[q];
        pk[q] = f2bf(vp[oo]);
      }
      const int sb = kb ^ ((o >> 1) & 3);
      *(ushort8x*)(dst + o * 32 + sb * 8) = pk;
    }
  }
}

// ---------------------------------------------------------------------------
// Kernel 2: logits -> softmax -> 16x16 solve -> power [4096][16]
// 64 threads/block = 4 batch rows x 16 lanes. Thread (r,i): logits row i.
// GE: thread (r,j) owns row j of M; pivots broadcast via __shfl in-wave.
// ---------------------------------------------------------------------------
__global__ __launch_bounds__(64) void power_kernel(
    const float* __restrict__ x, const float* __restrict__ Wd,
    const float* __restrict__ bd, float* __restrict__ power)
{
  __shared__ float S[4][16][16];       // dall[r][i][j]
  const int tid = threadIdx.x;         // 0..63
  const int r = tid >> 4;              // 0..3
  const int ci = tid & 15;             // citizen i (phase 1) / row j (phase 2)
  const int b = blockIdx.x * 4 + r;

  const float* xrow = x + (size_t)b * 1024;
  const float* wrow = Wd + (size_t)ci * 16384;   // Wd[ci][k][j], j contiguous

  float acc[16];
  #pragma unroll
  for (int j = 0; j < 16; ++j) acc[j] = bd[ci * 16 + j];

  for (int k = 0; k < 1024; k += 4) {
    float4 xv = *(const float4*)(xrow + k);
    #pragma unroll
    for (int kk = 0; kk < 4; ++kk) {
      const float xk = ((const float*)&xv)[kk];
      const float4* w4 = (const float4*)(wrow + (size_t)(k + kk) * 16);
      float4 w0 = w4[0], w1 = w4[1], w2 = w4[2], w3 = w4[3];
      acc[0]  += xk * w0.x; acc[1]  += xk * w0.y; acc[2]  += xk * w0.z; acc[3]  += xk * w0.w;
      acc[4]  += xk * w1.x; acc[5]  += xk * w1.y; acc[6]  += xk * w1.z; acc[7]  += xk * w1.w;
      acc[8]  += xk * w2.x; acc[9]  += xk * w2.y; acc[10] += xk * w2.z; acc[11] += xk * w2.w;
      acc[12] += xk * w3.x; acc[13] += xk * w3.y; acc[14] += xk * w3.z; acc[15] += xk * w3.w;
    }
  }

  // softmax over j (all in-register)
  float mx = acc[0];
  #pragma unroll
  for (int j = 1; j < 16; ++j) mx = fmaxf(mx, acc[j]);
  float sum = 0.f;
  #pragma unroll
  for (int j = 0; j < 16; ++j) { acc[j] = __expf(acc[j] - mx); sum += acc[j]; }
  const float inv = 1.0f / sum;
  #pragma unroll
  for (int j = 0; j < 16; ++j) S[r][ci][j] = acc[j] * inv;
  __syncthreads();

  // Gaussian elimination: M[j][c] = (c==j) ? 1 : -(1-eps)*dall[c][j]
  float mr[16];
  #pragma unroll
  for (int c = 0; c < 16; ++c)
    mr[c] = (c == ci) ? 1.0f : -(1.0f - EPSI) * S[r][c][ci];
  float rhs = 1.0f;
  const int lbase = tid & 48;

  #pragma unroll
  for (int t = 0; t < 15; ++t) {
    float pr[16];
    #pragma unroll
    for (int c = t; c < 16; ++c) pr[c] = __shfl(mr[c], lbase + t);
    const float prhs = __shfl(rhs, lbase + t);
    if (ci > t) {
      const float f = mr[t] / pr[t];
      #pragma unroll
      for (int c = t + 1; c < 16; ++c) mr[c] -= f * pr[c];
      rhs -= f * prhs;
    }
  }
  float px = 0.f;
  #pragma unroll
  for (int t = 15; t >= 0; --t) {
    const float cand = rhs / mr[t];
    const float xt = __shfl(cand, lbase + t);
    if (ci == t) px = xt;
    if (ci < t) rhs -= mr[t] * xt;
  }
  float ssum = px;
  ssum += __shfl_xor(ssum, 1);
  ssum += __shfl_xor(ssum, 2);
  ssum += __shfl_xor(ssum, 4);
  ssum += __shfl_xor(ssum, 8);

  power[(size_t)b * 16 + ci] =
      (1.0f - EPSI) * S[r][ci][ci] * px + (EPSI / 16.0f) * ssum;
}

// ---------------------------------------------------------------------------
// Kernel 3: y = X' @ W' via bf16 MFMA. 128x128 tile, BK=32, 256 thr (4 waves),
// split-K=4 (grid.z) + f32 atomicAdd epilogue. A reg-staged from x with
// power scale + bf16 cvt (LDS stride 40 u16 = 80B: 2-way-free banks).
// B via global_load_lds (layout pre-swizzled by convert kernel).
// z==0 runs one extra MFMA step folding in the `by` bias.
// ---------------------------------------------------------------------------
#define GASTR 40

__global__ __launch_bounds__(256) void gemm_kernel(
    const float* __restrict__ x, const u16* __restrict__ Bp,
    const float* __restrict__ power, const float* __restrict__ by,
    float* __restrict__ out)
{
  __shared__ __align__(16) u16 Al[128 * GASTR];   // 10240 B
  __shared__ __align__(16) u16 Bl[128 * 32];      // 8192 B, [col][32k] swizzled
  const int tid  = threadIdx.x;
  const int lane = tid & 63;
  const int wave = tid >> 6;
  const int row0 = blockIdx.x * 128;
  const int col0 = blockIdx.y * 128;
  const int z    = blockIdx.z;                    // K split 0..3
  const int arow = tid >> 1;                      // staging row 0..127
  const int ahalf = tid & 1;                      // staging k-half
  const int wr = wave >> 1, wc = wave & 1;
  const int l15 = lane & 15, l4 = lane >> 4;

  f32x4 acc[4][4];
  #pragma unroll
  for (int m = 0; m < 4; ++m)
    #pragma unroll
    for (int n = 0; n < 4; ++n)
      #pragma unroll
      for (int q = 0; q < 4; ++q) acc[m][n][q] = 0.0f;

  int aoff[4], boff[4];
  #pragma unroll
  for (int m = 0; m < 4; ++m)
    aoff[m] = (wr * 64 + m * 16 + l15) * GASTR + l4 * 8;
  #pragma unroll
  for (int n = 0; n < 4; ++n) {
    const int cl = wc * 64 + n * 16 + l15;
    boff[n] = cl * 32 + (l4 ^ ((cl >> 1) & 3)) * 8;
  }

  const float* xbase = x + (size_t)(row0 + arow) * 1024;
  const float* pbase = power + (size_t)(row0 + arow) * 16;
  u16* awr = Al + arow * GASTR + ahalf * 16;

  for (int kt = z * 128; kt < z * 128 + 128; ++kt) {
    { // stage A: 16 bf16 per thread, scaled by power[row][ii]
      const int ii = kt & 15, kc = kt >> 4;
      const float pw = pbase[ii];
      const float* xs = xbase + kc * 32 + ahalf * 16;
      float4 v0 = *(const float4*)(xs);
      float4 v1 = *(const float4*)(xs + 4);
      float4 v2 = *(const float4*)(xs + 8);
      float4 v3 = *(const float4*)(xs + 12);
      float tv[16];
      tv[0]=v0.x; tv[1]=v0.y; tv[2]=v0.z; tv[3]=v0.w;
      tv[4]=v1.x; tv[5]=v1.y; tv[6]=v1.z; tv[7]=v1.w;
      tv[8]=v2.x; tv[9]=v2.y; tv[10]=v2.z; tv[11]=v2.w;
      tv[12]=v3.x; tv[13]=v3.y; tv[14]=v3.z; tv[15]=v3.w;
      ushort8x p0, p1;
      #pragma unroll
      for (int q = 0; q < 8; ++q) {
        p0[q] = f2bf(tv[q] * pw);
        p1[q] = f2bf(tv[8 + q] * pw);
      }
      *(ushort8x*)awr = p0;
      *(ushort8x*)(awr + 8) = p1;
    }
    { // stage B: 8KB linear copy (swizzle pre-baked in Bp layout)
      const u16* gs = Bp + (size_t)kt * 32768 + col0 * 32 + wave * 1024 + lane * 8;
      u16* ld = Bl + wave * 1024;
      gload_lds16(gs, ld);
      gload_lds16(gs + 512, ld + 512);
    }
    __syncthreads();

    short8x af[4], bf[4];
    #pragma unroll
    for (int m = 0; m < 4; ++m) af[m] = *(const short8x*)(Al + aoff[m]);
    #pragma unroll
    for (int n = 0; n < 4; ++n) bf[n] = *(const short8x*)(Bl + boff[n]);
    #pragma unroll
    for (int m = 0; m < 4; ++m)
      #pragma unroll
      for (int n = 0; n < 4; ++n)
        acc[m][n] = __builtin_amdgcn_mfma_f32_16x16x32_bf16(
            af[m], bf[n], acc[m][n], 0, 0, 0);
    __syncthreads();
  }

  if (z == 0) {
    // bias MFMA step: A-ext[row][k<16] = power[row][k]; B-ext[k<16][o] = by[k][o]
    {
      ushort8x p0, p1;
      #pragma unroll
      for (int q = 0; q < 8; ++q) { p0[q] = 0; p1[q] = 0; }
      if (ahalf == 0) {
        #pragma unroll
        for (int q = 0; q < 8; ++q) {
          p0[q] = f2bf(pbase[q]);
          p1[q] = f2bf(pbase[8 + q]);
        }
      }
      *(ushort8x*)awr = p0;
      *(ushort8x*)(awr + 8) = p1;
    }
    {
      const int c = tid >> 1, hf = tid & 1;
      ushort8x q0, q1;
      #pragma unroll
      for (int q = 0; q < 8; ++q) { q0[q] = 0; q1[q] = 0; }
      if (hf == 0) {
        #pragma unroll
        for (int q = 0; q < 8; ++q) {
          q0[q] = f2bf(by[(size_t)q * 1024 + col0 + c]);
          q1[q] = f2bf(by[(size_t)(8 + q) * 1024 + col0 + c]);
        }
      }
      const int s0 = (hf * 2 + 0) ^ ((c >> 1) & 3);
      const int s1 = (hf * 2 + 1) ^ ((c >> 1) & 3);
      *(ushort8x*)(Bl + c * 32 + s0 * 8) = q0;
      *(ushort8x*)(Bl + c * 32 + s1 * 8) = q1;
    }
    __syncthreads();
    short8x af[4], bf[4];
    #pragma unroll
    for (int m = 0; m < 4; ++m) af[m] = *(const short8x*)(Al + aoff[m]);
    #pragma unroll
    for (int n = 0; n < 4; ++n) bf[n] = *(const short8x*)(Bl + boff[n]);
    #pragma unroll
    for (int m = 0; m < 4; ++m)
      #pragma unroll
      for (int n = 0; n < 4; ++n)
        acc[m][n] = __builtin_amdgcn_mfma_f32_16x16x32_bf16(
            af[m], bf[n], acc[m][n], 0, 0, 0);
  }

  // epilogue: C/D layout col = lane&15, row = (lane>>4)*4 + q
  #pragma unroll
  for (int m = 0; m < 4; ++m) {
    const int rb = row0 + wr * 64 + m * 16 + l4 * 4;
    #pragma unroll
    for (int n = 0; n < 4; ++n) {
      const int cg = col0 + wc * 64 + n * 16 + l15;
      #pragma unroll
      for (int q = 0; q < 4; ++q)
        atomicAdd(out + (size_t)(rb + q) * 1024 + cg, acc[m][n][q]);
    }
  }
}

// ---------------------------------------------------------------------------
extern "C" void kernel_launch(void* const* d_in, const int* in_sizes, int n_in,
                              void* d_out, int out_size, void* d_ws, size_t ws_size,
                              hipStream_t stream) {
  const float* x  = (const float*)d_in[0];
  const float* Wy = (const float*)d_in[1];
  const float* by = (const float*)d_in[2];
  const float* Wd = (const float*)d_in[3];
  const float* bd = (const float*)d_in[4];
  float* out = (float*)d_out;

  u16*   Bp    = (u16*)d_ws;                                  // 32 MB bf16 Wy
  float* power = (float*)((char*)d_ws + (size_t)32 * 1024 * 1024); // 256 KB

  hipMemsetAsync(d_out, 0, (size_t)out_size * sizeof(float), stream);
  convert_wy_kernel<<<512, 256, 0, stream>>>(Wy, Bp);
  power_kernel<<<1024, 64, 0, stream>>>(x, Wd, bd, power);
  gemm_kernel<<<dim3(32, 8, 4), 256, 0, stream>>>(x, Bp, power, by, out);
}

// Round 5
// 537.746 us; speedup vs baseline: 1.7912x; 1.7912x over previous
//
#include <hip/hip_runtime.h>
#include <hip/hip_bf16.h>
#include <stdint.h>

// LiquidEnsembleLayer on MI355X.
// Math: power_ext = pinv(I - D_no_diag) @ 1 reduces to a 16x16 linear solve
// (M is strictly column-diagonally-dominant => invertible; col 16 of the 17x17
//  extended system is e_n, so it block-triangularizes).
// power[i] = (1-eps)*dall[i,i]*p_i + (eps/16)*sum(p)
// y[b] = sum_i power[b,i] * (x[b] @ Wy[i] + by[i])
//      = [power-scaled replicated x] @ [Wy flattened]  (+ bias MFMA step)
//
// R1 -> R2: power_kernel (scalar logits GEMM, 505us, latency-starved) replaced
// by MFMA logits GEMM + solve.
// R2/R3 container deaths: suspected ws overflow (R2 used 38.5MB vs R1's proven
// 33.8MB). R4: fused logits+solve, footprint back to R1's 33,816,576 bytes.
// R4 -> R5: resubmit unchanged (R4 was GPUAcquisitionTimeout, never ran).

using u16 = unsigned short;
typedef __attribute__((ext_vector_type(8))) short short8x;
typedef __attribute__((ext_vector_type(8))) unsigned short ushort8x;
typedef __attribute__((ext_vector_type(4))) float f32x4;

#define EPSI 0.01f

__device__ __forceinline__ u16 f2bf(float f) {
  union { float fl; unsigned int u; } c; c.fl = f;
  unsigned int u = c.u;
  u += 0x7fffu + ((u >> 16) & 1u);   // RNE round to bf16
  return (u16)(u >> 16);
}

__device__ __forceinline__ void gload_lds16(const void* g, void* l) {
  __builtin_amdgcn_global_load_lds(
      (const __attribute__((address_space(1))) unsigned int*)g,
      (__attribute__((address_space(3))) unsigned int*)l, 16, 0, 0);
}

// ---------------------------------------------------------------------------
// Kernel 1: Wy f32 [16][1024][1024] -> bf16, GEMM-K-reordered + swizzled tiles.
// GEMM k-index: kt = kc*16 + ii (kc = chunk of 32 within DIN, ii = citizen).
// Tile layout: Bp[kt*32768 + o*32 + sb*8 + kr], sb = kb ^ ((o>>1)&3)
// (identical to R1 -- passed)
// ---------------------------------------------------------------------------
__global__ __launch_bounds__(256) void convert_wy_kernel(
    const float* __restrict__ Wy, u16* __restrict__ Bp)
{
  const int kt = blockIdx.x;           // 0..511
  const int ii = kt & 15;
  const int kc = kt >> 4;
  const int o0 = threadIdx.x * 4;
  const float* src = Wy + (size_t)ii * 1048576 + (size_t)(kc * 32) * 1024;
  u16* dst = Bp + (size_t)kt * 32768;

  #pragma unroll
  for (int kb = 0; kb < 4; ++kb) {
    float4 v[8];
    #pragma unroll
    for (int q = 0; q < 8; ++q)
      v[q] = *(const float4*)(src + (size_t)(kb * 8 + q) * 1024 + o0);
    #pragma unroll
    for (int oo = 0; oo < 4; ++oo) {
      const int o = o0 + oo;
      ushort8x pk;
      #pragma unroll
      for (int q = 0; q < 8; ++q) {
        const float* vp = (const float*)&v[q];
        pk[q] = f2bf(vp[oo]);
      }
      const int sb = kb ^ ((o >> 1) & 3);
      *(ushort8x*)(dst + o * 32 + sb * 8) = pk;
    }
  }
}

// ---------------------------------------------------------------------------
// Kernel 2 (fused): logits = x @ B (B[k][c]=Wd[c>>4][k][c&15]) via bf16 MFMA,
// then +bd, softmax, 16x16 GE solve -> power. ZERO extra workspace.
// Grid: 64 blocks x 256 thr (4 waves = 2x2). Block = 64 rows x 256 cols,
// BK=32, full K=1024 (no split-K, no atomics). Logits land in LDS (stride 260
// floats => <=2-way bank aliasing on MFMA-layout stores), solve runs in-block.
// ---------------------------------------------------------------------------
#define LASTR 40
#define SSTR  260

__global__ __launch_bounds__(256) void logits_solve_kernel(
    const float* __restrict__ x, const float* __restrict__ Wd,
    const float* __restrict__ bd, float* __restrict__ power)
{
  __shared__ __align__(16) u16 Al[64 * LASTR];   // 5120 B
  __shared__ __align__(16) u16 Bl[256 * 32];     // 16384 B
  __shared__ float Slog[64 * SSTR];              // 66560 B
  const int tid  = threadIdx.x;
  const int lane = tid & 63;
  const int wave = tid >> 6;
  const int row0 = blockIdx.x * 64;
  const int wr = wave >> 1, wc = wave & 1;   // wave tile: 32 rows x 128 cols
  const int l15 = lane & 15, l4 = lane >> 4;
  const int srow = tid >> 2, sq = tid & 3;   // A staging: row 0..63, k-quarter

  f32x4 acc[2][8];
  #pragma unroll
  for (int m = 0; m < 2; ++m)
    #pragma unroll
    for (int n = 0; n < 8; ++n)
      #pragma unroll
      for (int q = 0; q < 4; ++q) acc[m][n][q] = 0.0f;

  const float* xs_base = x + (size_t)(row0 + srow) * 1024 + sq * 8;
  u16* awr = Al + srow * LASTR + sq * 8;
  const int c = tid;                         // owned B column 0..255
  const float* wsrc = Wd + (size_t)(c >> 4) * 16384 + (c & 15);
  const int csw = (c >> 1) & 3;

  for (int it = 0; it < 32; ++it) {
    { // stage A: 8 bf16 per thread
      const float* xs = xs_base + it * 32;
      float4 v0 = *(const float4*)(xs);
      float4 v1 = *(const float4*)(xs + 4);
      ushort8x p;
      p[0]=f2bf(v0.x); p[1]=f2bf(v0.y); p[2]=f2bf(v0.z); p[3]=f2bf(v0.w);
      p[4]=f2bf(v1.x); p[5]=f2bf(v1.y); p[6]=f2bf(v1.z); p[7]=f2bf(v1.w);
      *(ushort8x*)awr = p;
    }
    { // stage B: Wd f32 (1MB, L2-resident) -> bf16 -> swizzled LDS
      #pragma unroll
      for (int k8 = 0; k8 < 4; ++k8) {
        ushort8x pk;
        #pragma unroll
        for (int r = 0; r < 8; ++r)
          pk[r] = f2bf(wsrc[(size_t)(it * 32 + k8 * 8 + r) * 16]);
        *(ushort8x*)(Bl + c * 32 + (k8 ^ csw) * 8) = pk;
      }
    }
    __syncthreads();

    short8x af[2], bf[8];
    #pragma unroll
    for (int m = 0; m < 2; ++m)
      af[m] = *(const short8x*)(Al + (wr * 32 + m * 16 + l15) * LASTR + l4 * 8);
    #pragma unroll
    for (int n = 0; n < 8; ++n) {
      const int cc = wc * 128 + n * 16 + l15;
      bf[n] = *(const short8x*)(Bl + cc * 32 + (l4 ^ ((cc >> 1) & 3)) * 8);
    }
    #pragma unroll
    for (int m = 0; m < 2; ++m)
      #pragma unroll
      for (int n = 0; n < 8; ++n)
        acc[m][n] = __builtin_amdgcn_mfma_f32_16x16x32_bf16(
            af[m], bf[n], acc[m][n], 0, 0, 0);
    __syncthreads();
  }

  // epilogue: logits -> LDS. C/D layout: col = lane&15, row = (lane>>4)*4+q
  #pragma unroll
  for (int m = 0; m < 2; ++m) {
    const int rb = wr * 32 + m * 16 + l4 * 4;
    #pragma unroll
    for (int n = 0; n < 8; ++n) {
      const int cg = wc * 128 + n * 16 + l15;
      #pragma unroll
      for (int q = 0; q < 4; ++q)
        Slog[(rb + q) * SSTR + cg] = acc[m][n][q];
    }
  }
  __syncthreads();

  // ---- solve phase: 16 batch rows at a time (each row owned by 16 lanes) ----
  const int ci = lane & 15;                  // citizen index
  const int bslot = wave * 4 + (lane >> 4);  // 0..15
  const int lbase = lane & 48;
  float bdr[16];
  #pragma unroll
  for (int j = 0; j < 16; ++j) bdr[j] = bd[ci * 16 + j];

  for (int brg = 0; brg < 4; ++brg) {
    const int bl = brg * 16 + bslot;         // local batch row 0..63
    float* srow_p = Slog + bl * SSTR;

    float dl[16];
    #pragma unroll
    for (int j = 0; j < 16; ++j) dl[j] = srow_p[ci * 16 + j] + bdr[j];

    // softmax over j (in-register)
    float mx = dl[0];
    #pragma unroll
    for (int j = 1; j < 16; ++j) mx = fmaxf(mx, dl[j]);
    float sum = 0.f;
    #pragma unroll
    for (int j = 0; j < 16; ++j) { dl[j] = __expf(dl[j] - mx); sum += dl[j]; }
    const float inv = 1.0f / sum;
    #pragma unroll
    for (int j = 0; j < 16; ++j) srow_p[ci * 16 + j] = dl[j] * inv;
    __syncthreads();

    // Gaussian elimination: M[j][c] = (c==j) ? 1 : -(1-eps)*dall[c][j]
    float mr[16];
    #pragma unroll
    for (int cc = 0; cc < 16; ++cc)
      mr[cc] = (cc == ci) ? 1.0f : -(1.0f - EPSI) * srow_p[cc * 16 + ci];
    const float ddiag = srow_p[ci * 16 + ci];   // dall[ci][ci] (LDS, not reg-idx)
    float rhs = 1.0f;

    #pragma unroll
    for (int t = 0; t < 15; ++t) {
      float pr[16];
      #pragma unroll
      for (int cc = t; cc < 16; ++cc) pr[cc] = __shfl(mr[cc], lbase + t);
      const float prhs = __shfl(rhs, lbase + t);
      if (ci > t) {
        const float f = mr[t] / pr[t];
        #pragma unroll
        for (int cc = t + 1; cc < 16; ++cc) mr[cc] -= f * pr[cc];
        rhs -= f * prhs;
      }
    }
    float px = 0.f;
    #pragma unroll
    for (int t = 15; t >= 0; --t) {
      const float cand = rhs / mr[t];
      const float xt = __shfl(cand, lbase + t);
      if (ci == t) px = xt;
      if (ci < t) rhs -= mr[t] * xt;
    }
    float ssum = px;
    ssum += __shfl_xor(ssum, 1);
    ssum += __shfl_xor(ssum, 2);
    ssum += __shfl_xor(ssum, 4);
    ssum += __shfl_xor(ssum, 8);

    power[(size_t)(row0 + bl) * 16 + ci] =
        (1.0f - EPSI) * ddiag * px + (EPSI / 16.0f) * ssum;
  }
}

// ---------------------------------------------------------------------------
// Kernel 3: y = X' @ W' via bf16 MFMA. 128x128 tile, BK=32, 256 thr (4 waves),
// split-K=4 (grid.z) + f32 atomicAdd epilogue. (identical to R1 -- passed)
// ---------------------------------------------------------------------------
#define GASTR 40

__global__ __launch_bounds__(256) void gemm_kernel(
    const float* __restrict__ x, const u16* __restrict__ Bp,
    const float* __restrict__ power, const float* __restrict__ by,
    float* __restrict__ out)
{
  __shared__ __align__(16) u16 Al[128 * GASTR];   // 10240 B
  __shared__ __align__(16) u16 Bl[128 * 32];      // 8192 B
  const int tid  = threadIdx.x;
  const int lane = tid & 63;
  const int wave = tid >> 6;
  const int row0 = blockIdx.x * 128;
  const int col0 = blockIdx.y * 128;
  const int z    = blockIdx.z;
  const int arow = tid >> 1;
  const int ahalf = tid & 1;
  const int wr = wave >> 1, wc = wave & 1;
  const int l15 = lane & 15, l4 = lane >> 4;

  f32x4 acc[4][4];
  #pragma unroll
  for (int m = 0; m < 4; ++m)
    #pragma unroll
    for (int n = 0; n < 4; ++n)
      #pragma unroll
      for (int q = 0; q < 4; ++q) acc[m][n][q] = 0.0f;

  int aoff[4], boff[4];
  #pragma unroll
  for (int m = 0; m < 4; ++m)
    aoff[m] = (wr * 64 + m * 16 + l15) * GASTR + l4 * 8;
  #pragma unroll
  for (int n = 0; n < 4; ++n) {
    const int cl = wc * 64 + n * 16 + l15;
    boff[n] = cl * 32 + (l4 ^ ((cl >> 1) & 3)) * 8;
  }

  const float* xbase = x + (size_t)(row0 + arow) * 1024;
  const float* pbase = power + (size_t)(row0 + arow) * 16;
  u16* awr = Al + arow * GASTR + ahalf * 16;

  for (int kt = z * 128; kt < z * 128 + 128; ++kt) {
    { // stage A: 16 bf16 per thread, scaled by power[row][ii]
      const int ii = kt & 15, kc = kt >> 4;
      const float pw = pbase[ii];
      const float* xs = xbase + kc * 32 + ahalf * 16;
      float4 v0 = *(const float4*)(xs);
      float4 v1 = *(const float4*)(xs + 4);
      float4 v2 = *(const float4*)(xs + 8);
      float4 v3 = *(const float4*)(xs + 12);
      float tv[16];
      tv[0]=v0.x; tv[1]=v0.y; tv[2]=v0.z; tv[3]=v0.w;
      tv[4]=v1.x; tv[5]=v1.y; tv[6]=v1.z; tv[7]=v1.w;
      tv[8]=v2.x; tv[9]=v2.y; tv[10]=v2.z; tv[11]=v2.w;
      tv[12]=v3.x; tv[13]=v3.y; tv[14]=v3.z; tv[15]=v3.w;
      ushort8x p0, p1;
      #pragma unroll
      for (int q = 0; q < 8; ++q) {
        p0[q] = f2bf(tv[q] * pw);
        p1[q] = f2bf(tv[8 + q] * pw);
      }
      *(ushort8x*)awr = p0;
      *(ushort8x*)(awr + 8) = p1;
    }
    { // stage B: 8KB linear copy (swizzle pre-baked in Bp layout)
      const u16* gs = Bp + (size_t)kt * 32768 + col0 * 32 + wave * 1024 + lane * 8;
      u16* ld = Bl + wave * 1024;
      gload_lds16(gs, ld);
      gload_lds16(gs + 512, ld + 512);
    }
    __syncthreads();

    short8x af[4], bf[4];
    #pragma unroll
    for (int m = 0; m < 4; ++m) af[m] = *(const short8x*)(Al + aoff[m]);
    #pragma unroll
    for (int n = 0; n < 4; ++n) bf[n] = *(const short8x*)(Bl + boff[n]);
    #pragma unroll
    for (int m = 0; m < 4; ++m)
      #pragma unroll
      for (int n = 0; n < 4; ++n)
        acc[m][n] = __builtin_amdgcn_mfma_f32_16x16x32_bf16(
            af[m], bf[n], acc[m][n], 0, 0, 0);
    __syncthreads();
  }

  if (z == 0) {
    {
      ushort8x p0, p1;
      #pragma unroll
      for (int q = 0; q < 8; ++q) { p0[q] = 0; p1[q] = 0; }
      if (ahalf == 0) {
        #pragma unroll
        for (int q = 0; q < 8; ++q) {
          p0[q] = f2bf(pbase[q]);
          p1[q] = f2bf(pbase[8 + q]);
        }
      }
      *(ushort8x*)awr = p0;
      *(ushort8x*)(awr + 8) = p1;
    }
    {
      const int cq = tid >> 1, hf = tid & 1;
      ushort8x q0, q1;
      #pragma unroll
      for (int q = 0; q < 8; ++q) { q0[q] = 0; q1[q] = 0; }
      if (hf == 0) {
        #pragma unroll
        for (int q = 0; q < 8; ++q) {
          q0[q] = f2bf(by[(size_t)q * 1024 + col0 + cq]);
          q1[q] = f2bf(by[(size_t)(8 + q) * 1024 + col0 + cq]);
        }
      }
      const int s0 = (hf * 2 + 0) ^ ((cq >> 1) & 3);
      const int s1 = (hf * 2 + 1) ^ ((cq >> 1) & 3);
      *(ushort8x*)(Bl + cq * 32 + s0 * 8) = q0;
      *(ushort8x*)(Bl + cq * 32 + s1 * 8) = q1;
    }
    __syncthreads();
    short8x af[4], bf[4];
    #pragma unroll
    for (int m = 0; m < 4; ++m) af[m] = *(const short8x*)(Al + aoff[m]);
    #pragma unroll
    for (int n = 0; n < 4; ++n) bf[n] = *(const short8x*)(Bl + boff[n]);
    #pragma unroll
    for (int m = 0; m < 4; ++m)
      #pragma unroll
      for (int n = 0; n < 4; ++n)
        acc[m][n] = __builtin_amdgcn_mfma_f32_16x16x32_bf16(
            af[m], bf[n], acc[m][n], 0, 0, 0);
  }

  #pragma unroll
  for (int m = 0; m < 4; ++m) {
    const int rb = row0 + wr * 64 + m * 16 + l4 * 4;
    #pragma unroll
    for (int n = 0; n < 4; ++n) {
      const int cg = col0 + wc * 64 + n * 16 + l15;
      #pragma unroll
      for (int q = 0; q < 4; ++q)
        atomicAdd(out + (size_t)(rb + q) * 1024 + cg, acc[m][n][q]);
    }
  }
}

// ---------------------------------------------------------------------------
extern "C" void kernel_launch(void* const* d_in, const int* in_sizes, int n_in,
                              void* d_out, int out_size, void* d_ws, size_t ws_size,
                              hipStream_t stream) {
  const float* x  = (const float*)d_in[0];
  const float* Wy = (const float*)d_in[1];
  const float* by = (const float*)d_in[2];
  const float* Wd = (const float*)d_in[3];
  const float* bd = (const float*)d_in[4];
  float* out = (float*)d_out;

  char* ws = (char*)d_ws;
  u16*   Bp    = (u16*)ws;                       // 32 MB (bf16 Wy, retiled)
  float* power = (float*)(ws + 33554432);        // 256 KB
  // total ws usage: 33,816,576 bytes == R1's proven footprint

  hipMemsetAsync(d_out, 0, (size_t)out_size * sizeof(float), stream);
  convert_wy_kernel<<<512, 256, 0, stream>>>(Wy, Bp);
  logits_solve_kernel<<<64, 256, 0, stream>>>(x, Wd, bd, power);
  gemm_kernel<<<dim3(32, 8, 4), 256, 0, stream>>>(x, Bp, power, by, out);
}

// Round 7
// 402.337 us; speedup vs baseline: 2.3940x; 1.3366x over previous
//
#include <hip/hip_runtime.h>
#include <hip/hip_bf16.h>
#include <stdint.h>

// LiquidEnsembleLayer on MI355X.
// power_ext = pinv(I-D_no_diag)@1 -> 16x16 solve; y = [power-scaled repl. x]@[Wy flat].
// R5 counters: gemm LDS-bound (MfmaUtil 16%, 1.68e7 bank conflicts, 2 barriers/iter).
// R6: conflict-free [koct][col][8] LDS layout, BN=256 + 8 waves, 2-phase
// single-barrier pipeline, cvt_pk staging, coalesced Wd staging in logits.
// R6 -> R7: never ran (GPU timeout); fixed units bug in Bl2 double-buffer
// offset (pb*16384 u16 -> pb*8192 u16; was writing 16KB past Bl2 on odd t).

using u16 = unsigned short;
typedef __attribute__((ext_vector_type(8))) short short8x;
typedef __attribute__((ext_vector_type(4))) float f32x4;

#define EPSI 0.01f

__device__ __forceinline__ u16 f2bf(float f) {
  union { float fl; unsigned int u; } c; c.fl = f;
  unsigned int u = c.u;
  u += 0x7fffu + ((u >> 16) & 1u);
  return (u16)(u >> 16);
}

__device__ __forceinline__ unsigned int cvtpk(float lo, float hi) {
  unsigned int r;
  asm("v_cvt_pk_bf16_f32 %0, %1, %2" : "=v"(r) : "v"(lo), "v"(hi));
  return r;
}

// 8 floats -> short8x (bf16 RNE) via 4x v_cvt_pk_bf16_f32
__device__ __forceinline__ short8x cvt8(const float* v) {
  union { short8x s; unsigned int u[4]; } r;
  r.u[0] = cvtpk(v[0], v[1]); r.u[1] = cvtpk(v[2], v[3]);
  r.u[2] = cvtpk(v[4], v[5]); r.u[3] = cvtpk(v[6], v[7]);
  return r.s;
}

__device__ __forceinline__ void gload_lds16(const void* g, void* l) {
  __builtin_amdgcn_global_load_lds(
      (const __attribute__((address_space(1))) unsigned int*)g,
      (__attribute__((address_space(3))) unsigned int*)l, 16, 0, 0);
}

// ---------------------------------------------------------------------------
// Kernel 1: Wy f32 [16][1024][1024] -> bf16, layout Bp[kt][sb][o][kr]
// kt = kc*16+ii (covers din kc*32..+32 of citizen ii), sb = k-oct (k%32)/8,
// kr = k%8, o = output col. Per (kt,sb): 1024 cols contiguous -> linear
// global_load_lds staging AND conflict-free b128 frag reads.
// ---------------------------------------------------------------------------
__global__ __launch_bounds__(256) void convert_wy_kernel(
    const float* __restrict__ Wy, u16* __restrict__ Bp)
{
  const int kt = blockIdx.x;           // 0..511
  const int ii = kt & 15;
  const int kc = kt >> 4;
  const int o0 = threadIdx.x * 4;
  const float* src = Wy + (size_t)ii * 1048576 + (size_t)(kc * 32) * 1024;
  u16* dst = Bp + (size_t)kt * 32768;

  #pragma unroll
  for (int kb = 0; kb < 4; ++kb) {
    float4 v[8];
    #pragma unroll
    for (int q = 0; q < 8; ++q)
      v[q] = *(const float4*)(src + (size_t)(kb * 8 + q) * 1024 + o0);
    #pragma unroll
    for (int oo = 0; oo < 4; ++oo) {
      float tv[8];
      #pragma unroll
      for (int q = 0; q < 8; ++q) tv[q] = ((const float*)&v[q])[oo];
      *(short8x*)(dst + kb * 8192 + (o0 + oo) * 8) = cvt8(tv);
    }
  }
}

// ---------------------------------------------------------------------------
// Kernel 2 (fused): logits = x @ Wd' via bf16 MFMA, then +bd, softmax,
// 16x16 GE solve -> power. 64 blocks x 256 thr (4 waves 2x2), 64 rows/block.
// Wd chunk staged COALESCED (float4) into f32 LDS bounce each BK=32 step;
// B-frags converted in-register from the bounce. Zero extra workspace.
// ---------------------------------------------------------------------------
#define SSTR 260

__global__ __launch_bounds__(256) void logits_solve_kernel(
    const float* __restrict__ x, const float* __restrict__ Wd,
    const float* __restrict__ bd, float* __restrict__ power)
{
  __shared__ float Sw[16640];                    // 66.56KB: Wd bounce / logits
  __shared__ __align__(16) u16 Al2[4][64][8];    // 4KB  [koct][row][kr]
  const int tid  = threadIdx.x;
  const int lane = tid & 63;
  const int wave = tid >> 6;                 // 0..3
  const int row0 = blockIdx.x * 64;
  const int wr = wave >> 1, wc = wave & 1;   // wave: 32 rows x 128 cols
  const int l15 = lane & 15, l4 = lane >> 4;

  f32x4 acc[2][8];
  #pragma unroll
  for (int m = 0; m < 2; ++m)
    #pragma unroll
    for (int n = 0; n < 8; ++n)
      #pragma unroll
      for (int q = 0; q < 4; ++q) acc[m][n][q] = 0.0f;

  const int wi = tid >> 4, t16 = tid & 15;   // Wd stage: citizen, 16-lane slot

  for (int it = 0; it < 32; ++it) {
    // coalesced Wd chunk load: [16 i][32 k][16 j] = 8192 f32
    const float* wbase = Wd + (size_t)wi * 16384 + it * 512 + t16 * 4;
    float4 wv[8];
    #pragma unroll
    for (int r = 0; r < 8; ++r) wv[r] = *(const float4*)(wbase + r * 64);
    // x chunk: row = row0+lane, k-oct = wave
    const float* xs = x + (size_t)(row0 + lane) * 1024 + it * 32 + wave * 8;
    float4 xa = *(const float4*)(xs);
    float4 xb = *(const float4*)(xs + 4);

    __syncthreads();   // previous iteration's Sw/Al2 reads complete
    #pragma unroll
    for (int r = 0; r < 8; ++r)
      *(float4*)(Sw + wi * 512 + r * 64 + t16 * 4) = wv[r];
    {
      float tv[8];
      tv[0]=xa.x; tv[1]=xa.y; tv[2]=xa.z; tv[3]=xa.w;
      tv[4]=xb.x; tv[5]=xb.y; tv[6]=xb.z; tv[7]=xb.w;
      *(short8x*)&Al2[wave][lane][0] = cvt8(tv);
    }
    __syncthreads();

    short8x af[2], bf[8];
    #pragma unroll
    for (int m = 0; m < 2; ++m)
      af[m] = *(const short8x*)&Al2[l4][wr * 32 + m * 16 + l15][0];
    #pragma unroll
    for (int n = 0; n < 8; ++n) {
      const int i2 = wc * 8 + n;             // citizen (uniform per frag)
      const float* sp = Sw + i2 * 512 + l4 * 128 + l15;
      float f[8];
      #pragma unroll
      for (int kr = 0; kr < 8; ++kr) f[kr] = sp[kr * 16];
      bf[n] = cvt8(f);
    }
    #pragma unroll
    for (int m = 0; m < 2; ++m)
      #pragma unroll
      for (int n = 0; n < 8; ++n)
        acc[m][n] = __builtin_amdgcn_mfma_f32_16x16x32_bf16(
            af[m], bf[n], acc[m][n], 0, 0, 0);
  }

  __syncthreads();   // last bounce reads complete before logits overwrite Sw
  #pragma unroll
  for (int m = 0; m < 2; ++m) {
    const int rb = wr * 32 + m * 16 + l4 * 4;
    #pragma unroll
    for (int n = 0; n < 8; ++n) {
      const int cg = wc * 128 + n * 16 + l15;
      #pragma unroll
      for (int q = 0; q < 4; ++q)
        Sw[(rb + q) * SSTR + cg] = acc[m][n][q];
    }
  }
  __syncthreads();

  // ---- solve: 16 batch rows per pass, each row owned by 16 lanes ----
  const int ci = lane & 15;
  const int bslot = wave * 4 + (lane >> 4);
  const int lbase = lane & 48;
  float bdr[16];
  #pragma unroll
  for (int j = 0; j < 16; ++j) bdr[j] = bd[ci * 16 + j];

  for (int brg = 0; brg < 4; ++brg) {
    const int bl = brg * 16 + bslot;
    float* srow_p = Sw + bl * SSTR;

    float dl[16];
    #pragma unroll
    for (int j = 0; j < 16; ++j) dl[j] = srow_p[ci * 16 + j] + bdr[j];

    float mx = dl[0];
    #pragma unroll
    for (int j = 1; j < 16; ++j) mx = fmaxf(mx, dl[j]);
    float sum = 0.f;
    #pragma unroll
    for (int j = 0; j < 16; ++j) { dl[j] = __expf(dl[j] - mx); sum += dl[j]; }
    const float inv = 1.0f / sum;
    #pragma unroll
    for (int j = 0; j < 16; ++j) srow_p[ci * 16 + j] = dl[j] * inv;
    __syncthreads();

    float mr[16];
    #pragma unroll
    for (int cc = 0; cc < 16; ++cc)
      mr[cc] = (cc == ci) ? 1.0f : -(1.0f - EPSI) * srow_p[cc * 16 + ci];
    const float ddiag = srow_p[ci * 16 + ci];
    float rhs = 1.0f;

    #pragma unroll
    for (int t = 0; t < 15; ++t) {
      float pr[16];
      #pragma unroll
      for (int cc = t; cc < 16; ++cc) pr[cc] = __shfl(mr[cc], lbase + t);
      const float prhs = __shfl(rhs, lbase + t);
      if (ci > t) {
        const float f = mr[t] / pr[t];
        #pragma unroll
        for (int cc = t + 1; cc < 16; ++cc) mr[cc] -= f * pr[cc];
        rhs -= f * prhs;
      }
    }
    float px = 0.f;
    #pragma unroll
    for (int t = 15; t >= 0; --t) {
      const float cand = rhs / mr[t];
      const float xt = __shfl(cand, lbase + t);
      if (ci == t) px = xt;
      if (ci < t) rhs -= mr[t] * xt;
    }
    float ssum = px;
    ssum += __shfl_xor(ssum, 1);
    ssum += __shfl_xor(ssum, 2);
    ssum += __shfl_xor(ssum, 4);
    ssum += __shfl_xor(ssum, 8);

    power[(size_t)(row0 + bl) * 16 + ci] =
        (1.0f - EPSI) * ddiag * px + (EPSI / 16.0f) * ssum;
  }
}

// ---------------------------------------------------------------------------
// Kernel 3: y = X' @ W'. 128x256 tile, BK=32, 512 thr (8 waves 2x4),
// split-K=4 (grid.z). 2-phase pipeline: stage t+1 (gload_lds B, reg->LDS A)
// before computing t; ONE barrier per K-step. Conflict-free [koct][col][8]
// LDS layout for both operands. power row cached in padded LDS. f32 atomicAdd
// epilogue; z==0 folds `by` bias via one extra MFMA step.
// ---------------------------------------------------------------------------
__global__ __launch_bounds__(512, 4) void gemm_kernel(
    const float* __restrict__ x, const u16* __restrict__ Bp,
    const float* __restrict__ power, const float* __restrict__ by,
    float* __restrict__ out)
{
  __shared__ __align__(16) u16 Al2[2][4][128][8];  // 16 KB
  __shared__ __align__(16) u16 Bl2[2][4][256][8];  // 32 KB
  __shared__ float Pl[128][17];                    // 8.7 KB, pad 17: free banks

  const int tid  = threadIdx.x;
  const int lane = tid & 63;
  const int wave = tid >> 6;                  // 0..7
  const int row0 = blockIdx.x * 128;
  const int col0 = blockIdx.y * 256;
  const int z    = blockIdx.z;
  const int wr = wave >> 2, wc = wave & 3;    // wave tile 64 rows x 64 cols
  const int l15 = lane & 15, l4 = lane >> 4;
  const int aq = tid >> 7, arow = tid & 127;  // A stage: k-oct plane, row

  // stage power rows -> Pl (coalesced float4)
  {
    const int pr = tid >> 2, pj = (tid & 3) * 4;
    float4 pv = *(const float4*)(power + (size_t)(row0 + pr) * 16 + pj);
    Pl[pr][pj] = pv.x; Pl[pr][pj + 1] = pv.y;
    Pl[pr][pj + 2] = pv.z; Pl[pr][pj + 3] = pv.w;
  }

  f32x4 acc[4][4];
  #pragma unroll
  for (int m = 0; m < 4; ++m)
    #pragma unroll
    for (int n = 0; n < 4; ++n)
      #pragma unroll
      for (int q = 0; q < 4; ++q) acc[m][n][q] = 0.0f;

  const float* xrow = x + (size_t)(row0 + arow) * 1024 + aq * 8;
  u16* const blbase = (u16*)Bl2;              // per-buffer stride: 8192 u16
  float xv[8];

  __syncthreads();   // Pl ready

  // prologue: stage t=0 into buf0
  {
    const int kt0 = z * 128;
    const float* xs = xrow + (kt0 >> 4) * 32;
    float4 a = *(const float4*)(xs), b = *(const float4*)(xs + 4);
    xv[0]=a.x; xv[1]=a.y; xv[2]=a.z; xv[3]=a.w;
    xv[4]=b.x; xv[5]=b.y; xv[6]=b.z; xv[7]=b.w;
    const u16* bsrc = Bp + (size_t)kt0 * 32768;
    #pragma unroll
    for (int q = 0; q < 2; ++q) {
      const int g = wave * 2 + q;
      gload_lds16(bsrc + (g >> 2) * 8192 + (col0 + (g & 3) * 64) * 8 + lane * 8,
                  blbase + g * 512 + lane * 8);
    }
    const float pw = Pl[arow][0];
    float tv[8];
    #pragma unroll
    for (int e = 0; e < 8; ++e) tv[e] = xv[e] * pw;
    *(short8x*)&Al2[0][aq][arow][0] = cvt8(tv);
  }
  __syncthreads();

  for (int t = 0; t < 128; ++t) {
    const int cb = t & 1;
    if (t < 127) {                 // stage t+1 into buf cb^1
      const int tn = t + 1, ktn = z * 128 + tn, iin = tn & 15, pb = tn & 1;
      const u16* bsrc = Bp + (size_t)ktn * 32768;
      #pragma unroll
      for (int q = 0; q < 2; ++q) {
        const int g = wave * 2 + q;
        gload_lds16(bsrc + (g >> 2) * 8192 + (col0 + (g & 3) * 64) * 8 + lane * 8,
                    blbase + pb * 8192 + g * 512 + lane * 8);
      }
      if (iin == 0) {              // new kc: reload x chunk (uniform branch)
        const float* xs = xrow + (ktn >> 4) * 32;
        float4 a = *(const float4*)(xs), b = *(const float4*)(xs + 4);
        xv[0]=a.x; xv[1]=a.y; xv[2]=a.z; xv[3]=a.w;
        xv[4]=b.x; xv[5]=b.y; xv[6]=b.z; xv[7]=b.w;
      }
      const float pw = Pl[arow][iin];
      float tv[8];
      #pragma unroll
      for (int e = 0; e < 8; ++e) tv[e] = xv[e] * pw;
      *(short8x*)&Al2[pb][aq][arow][0] = cvt8(tv);
    }
    // compute t from buf cb (frag reads conflict-free: lanes 0-15 contiguous)
    short8x af[4], bf[4];
    #pragma unroll
    for (int m = 0; m < 4; ++m)
      af[m] = *(const short8x*)&Al2[cb][l4][wr * 64 + m * 16 + l15][0];
    #pragma unroll
    for (int n = 0; n < 4; ++n)
      bf[n] = *(const short8x*)&Bl2[cb][l4][wc * 64 + n * 16 + l15][0];
    #pragma unroll
    for (int m = 0; m < 4; ++m)
      #pragma unroll
      for (int n = 0; n < 4; ++n)
        acc[m][n] = __builtin_amdgcn_mfma_f32_16x16x32_bf16(
            af[m], bf[n], acc[m][n], 0, 0, 0);
    __syncthreads();
  }

  if (z == 0) {   // bias fold: A-ext[row][k<16]=power[row][k]; B-ext[k<16][o]=by[k][o]
    {
      float tv[8];
      #pragma unroll
      for (int e = 0; e < 8; ++e)
        tv[e] = (aq < 2) ? Pl[arow][aq * 8 + e] : 0.0f;
      *(short8x*)&Al2[0][aq][arow][0] = cvt8(tv);
    }
    #pragma unroll
    for (int cpass = 0; cpass < 2; ++cpass) {
      const int cell = tid + cpass * 512;
      const int sb = cell >> 8, cl = cell & 255;
      union { short8x s; u16 h[8]; } p;
      #pragma unroll
      for (int r = 0; r < 8; ++r)
        p.h[r] = (sb < 2) ? f2bf(by[(size_t)(sb * 8 + r) * 1024 + col0 + cl])
                          : (u16)0;
      *(short8x*)&Bl2[0][sb][cl][0] = p.s;
    }
    __syncthreads();
    short8x af[4], bf[4];
    #pragma unroll
    for (int m = 0; m < 4; ++m)
      af[m] = *(const short8x*)&Al2[0][l4][wr * 64 + m * 16 + l15][0];
    #pragma unroll
    for (int n = 0; n < 4; ++n)
      bf[n] = *(const short8x*)&Bl2[0][l4][wc * 64 + n * 16 + l15][0];
    #pragma unroll
    for (int m = 0; m < 4; ++m)
      #pragma unroll
      for (int n = 0; n < 4; ++n)
        acc[m][n] = __builtin_amdgcn_mfma_f32_16x16x32_bf16(
            af[m], bf[n], acc[m][n], 0, 0, 0);
  }

  // epilogue: C/D layout col = lane&15, row = (lane>>4)*4 + q
  #pragma unroll
  for (int m = 0; m < 4; ++m) {
    const int rb = row0 + wr * 64 + m * 16 + l4 * 4;
    #pragma unroll
    for (int n = 0; n < 4; ++n) {
      const int cg = col0 + wc * 64 + n * 16 + l15;
      #pragma unroll
      for (int q = 0; q < 4; ++q)
        atomicAdd(out + (size_t)(rb + q) * 1024 + cg, acc[m][n][q]);
    }
  }
}

// ---------------------------------------------------------------------------
extern "C" void kernel_launch(void* const* d_in, const int* in_sizes, int n_in,
                              void* d_out, int out_size, void* d_ws, size_t ws_size,
                              hipStream_t stream) {
  const float* x  = (const float*)d_in[0];
  const float* Wy = (const float*)d_in[1];
  const float* by = (const float*)d_in[2];
  const float* Wd = (const float*)d_in[3];
  const float* bd = (const float*)d_in[4];
  float* out = (float*)d_out;

  char* ws = (char*)d_ws;
  u16*   Bp    = (u16*)ws;                       // 32 MB (bf16 Wy, retiled)
  float* power = (float*)(ws + 33554432);        // 256 KB
  // total ws usage: 33,816,576 bytes (R1-proven footprint)

  hipMemsetAsync(d_out, 0, (size_t)out_size * sizeof(float), stream);
  convert_wy_kernel<<<512, 256, 0, stream>>>(Wy, Bp);
  logits_solve_kernel<<<64, 256, 0, stream>>>(x, Wd, bd, power);
  gemm_kernel<<<dim3(32, 4, 4), 512, 0, stream>>>(x, Bp, power, by, out);
}

// Round 9
// 316.485 us; speedup vs baseline: 3.0434x; 1.2713x over previous
//
#include <hip/hip_runtime.h>
#include <hip/hip_bf16.h>
#include <stdint.h>

// LiquidEnsembleLayer on MI355X.
// power_ext = pinv(I-D_no_diag)@1 -> 16x16 solve; y = [power-scaled repl. x]@[Wy flat].
// R7 counters: gemm MfmaUtil 35% -- LDS-read bound (64x64 wave tile: 1024cy
// LDS vs 310cy MFMA per CU-iter). logits_solve 225us, VALUBusy 0.14% (latency).
// R9: (a) logits_solve: direct global->reg MFMA, no LDS staging, no K barriers
//     (Wd is 1MB L2-resident; staging was pure overhead).
//     (b) gemm: wave tile 64x64 -> 64x128 (4 waves/block, acc 4x8): LDS reads
//     12KB/524KFLOP -> MFMA becomes critical pipe (~57% ceiling).
//     (c) gemm: bijective XCD swizzle (each XCD owns 2 (col,z) panels).

using u16 = unsigned short;
typedef __attribute__((ext_vector_type(8))) short short8x;
typedef __attribute__((ext_vector_type(4))) float f32x4;

#define EPSI 0.01f

__device__ __forceinline__ u16 f2bf(float f) {
  union { float fl; unsigned int u; } c; c.fl = f;
  unsigned int u = c.u;
  u += 0x7fffu + ((u >> 16) & 1u);
  return (u16)(u >> 16);
}

__device__ __forceinline__ unsigned int cvtpk(float lo, float hi) {
  unsigned int r;
  asm("v_cvt_pk_bf16_f32 %0, %1, %2" : "=v"(r) : "v"(lo), "v"(hi));
  return r;
}

// 8 floats -> short8x (bf16 RNE) via 4x v_cvt_pk_bf16_f32
__device__ __forceinline__ short8x cvt8(const float* v) {
  union { short8x s; unsigned int u[4]; } r;
  r.u[0] = cvtpk(v[0], v[1]); r.u[1] = cvtpk(v[2], v[3]);
  r.u[2] = cvtpk(v[4], v[5]); r.u[3] = cvtpk(v[6], v[7]);
  return r.s;
}

__device__ __forceinline__ void gload_lds16(const void* g, void* l) {
  __builtin_amdgcn_global_load_lds(
      (const __attribute__((address_space(1))) unsigned int*)g,
      (__attribute__((address_space(3))) unsigned int*)l, 16, 0, 0);
}

// ---------------------------------------------------------------------------
// Kernel 1: Wy f32 [16][1024][1024] -> bf16, layout Bp[kt][sb][o][kr]
// kt = kc*16+ii, sb = (k%32)/8, kr = k%8, o = output col. (R7-proven)
// ---------------------------------------------------------------------------
__global__ __launch_bounds__(256) void convert_wy_kernel(
    const float* __restrict__ Wy, u16* __restrict__ Bp)
{
  const int kt = blockIdx.x;           // 0..511
  const int ii = kt & 15;
  const int kc = kt >> 4;
  const int o0 = threadIdx.x * 4;
  const float* src = Wy + (size_t)ii * 1048576 + (size_t)(kc * 32) * 1024;
  u16* dst = Bp + (size_t)kt * 32768;

  #pragma unroll
  for (int kb = 0; kb < 4; ++kb) {
    float4 v[8];
    #pragma unroll
    for (int q = 0; q < 8; ++q)
      v[q] = *(const float4*)(src + (size_t)(kb * 8 + q) * 1024 + o0);
    #pragma unroll
    for (int oo = 0; oo < 4; ++oo) {
      float tv[8];
      #pragma unroll
      for (int q = 0; q < 8; ++q) tv[q] = ((const float*)&v[q])[oo];
      *(short8x*)(dst + kb * 8192 + (o0 + oo) * 8) = cvt8(tv);
    }
  }
}

// ---------------------------------------------------------------------------
// Kernel 2: logits(16 rows x 256 cols, K=1024) via bf16 MFMA with DIRECT
// global->register fragment loads (no LDS staging, no K-loop barriers;
// Wd is 1MB = L2-resident), then +bd, softmax, 16x16 GE solve -> power.
// 256 blocks x 256 thr (4 waves); wave w owns cols w*64..+64 (citizens w*4..+4).
// A-frag: row=l15, k=l4*8+kr (validated layout). B-frag: col=l15, same k.
// ---------------------------------------------------------------------------
__global__ __launch_bounds__(256) void logits_solve_kernel(
    const float* __restrict__ x, const float* __restrict__ Wd,
    const float* __restrict__ bd, float* __restrict__ power)
{
  __shared__ float Slog[16][272];            // 17.4 KB
  const int tid  = threadIdx.x;
  const int lane = tid & 63;
  const int wave = tid >> 6;                 // 0..3
  const int row0 = blockIdx.x * 16;
  const int l15 = lane & 15, l4 = lane >> 4;

  f32x4 acc[4];
  #pragma unroll
  for (int n = 0; n < 4; ++n)
    #pragma unroll
    for (int q = 0; q < 4; ++q) acc[n][q] = 0.0f;

  const float* xb = x + (size_t)(row0 + l15) * 1024 + l4 * 8;
  const float* wb0 = Wd + (size_t)(wave * 4) * 16384 + (size_t)(l4 * 8) * 16 + l15;

  for (int it = 0; it < 32; ++it) {
    float4 a0 = *(const float4*)(xb + it * 32);
    float4 a1 = *(const float4*)(xb + it * 32 + 4);
    float av[8];
    av[0]=a0.x; av[1]=a0.y; av[2]=a0.z; av[3]=a0.w;
    av[4]=a1.x; av[5]=a1.y; av[6]=a1.z; av[7]=a1.w;
    const short8x af = cvt8(av);
    #pragma unroll
    for (int n = 0; n < 4; ++n) {
      const float* p = wb0 + (size_t)n * 16384 + (size_t)it * 512;
      float f[8];
      #pragma unroll
      for (int kr = 0; kr < 8; ++kr) f[kr] = p[kr * 16];
      acc[n] = __builtin_amdgcn_mfma_f32_16x16x32_bf16(af, cvt8(f), acc[n], 0, 0, 0);
    }
  }

  // epilogue: D row = l4*4+q, col = n*16+l15 (within wave's 64-col group)
  #pragma unroll
  for (int n = 0; n < 4; ++n)
    #pragma unroll
    for (int q = 0; q < 4; ++q)
      Slog[l4 * 4 + q][wave * 64 + n * 16 + l15] = acc[n][q];
  __syncthreads();

  // ---- solve: 16 rows x 16 citizens = 256 threads, single pass ----
  const int ci = lane & 15;                  // citizen
  const int r  = wave * 4 + (lane >> 4);     // batch row 0..15
  const int lbase = lane & 48;
  float* srow_p = &Slog[r][0];

  float bdr[16];
  #pragma unroll
  for (int j = 0; j < 16; ++j) bdr[j] = bd[ci * 16 + j];

  float dl[16];
  #pragma unroll
  for (int j = 0; j < 16; ++j) dl[j] = srow_p[ci * 16 + j] + bdr[j];

  float mx = dl[0];
  #pragma unroll
  for (int j = 1; j < 16; ++j) mx = fmaxf(mx, dl[j]);
  float sum = 0.f;
  #pragma unroll
  for (int j = 0; j < 16; ++j) { dl[j] = __expf(dl[j] - mx); sum += dl[j]; }
  const float inv = 1.0f / sum;
  #pragma unroll
  for (int j = 0; j < 16; ++j) srow_p[ci * 16 + j] = dl[j] * inv;
  __syncthreads();

  // Gaussian elimination: M[j][c] = (c==j) ? 1 : -(1-eps)*dall[c][j]
  float mr[16];
  #pragma unroll
  for (int cc = 0; cc < 16; ++cc)
    mr[cc] = (cc == ci) ? 1.0f : -(1.0f - EPSI) * srow_p[cc * 16 + ci];
  const float ddiag = srow_p[ci * 16 + ci];
  float rhs = 1.0f;

  #pragma unroll
  for (int t = 0; t < 15; ++t) {
    float pr[16];
    #pragma unroll
    for (int cc = t; cc < 16; ++cc) pr[cc] = __shfl(mr[cc], lbase + t);
    const float prhs = __shfl(rhs, lbase + t);
    if (ci > t) {
      const float f = mr[t] / pr[t];
      #pragma unroll
      for (int cc = t + 1; cc < 16; ++cc) mr[cc] -= f * pr[cc];
      rhs -= f * prhs;
    }
  }
  float px = 0.f;
  #pragma unroll
  for (int t = 15; t >= 0; --t) {
    const float cand = rhs / mr[t];
    const float xt = __shfl(cand, lbase + t);
    if (ci == t) px = xt;
    if (ci < t) rhs -= mr[t] * xt;
  }
  float ssum = px;
  ssum += __shfl_xor(ssum, 1);
  ssum += __shfl_xor(ssum, 2);
  ssum += __shfl_xor(ssum, 4);
  ssum += __shfl_xor(ssum, 8);

  power[(size_t)(row0 + r) * 16 + ci] =
      (1.0f - EPSI) * ddiag * px + (EPSI / 16.0f) * ssum;
}

// ---------------------------------------------------------------------------
// Kernel 3: y = X' @ W'. 128x256 tile, BK=32, 256 thr (4 waves 2x2, wave tile
// 64x128 -> acc 4x8), split-K=4. 2-phase single-barrier pipeline, conflict-free
// [koct][col][8] LDS, bijective XCD swizzle. 2 blocks/CU (57KB LDS).
// z==0 folds `by` bias via one extra MFMA step. f32 atomicAdd epilogue.
// ---------------------------------------------------------------------------
__global__ __launch_bounds__(256, 2) void gemm_kernel(
    const float* __restrict__ x, const u16* __restrict__ Bp,
    const float* __restrict__ power, const float* __restrict__ by,
    float* __restrict__ out)
{
  __shared__ __align__(16) u16 Al2[2][4][128][8];  // 16 KB
  __shared__ __align__(16) u16 Bl2[2][4][256][8];  // 32 KB
  __shared__ float Pl[128][17];                    // 8.7 KB

  const int tid  = threadIdx.x;
  const int lane = tid & 63;
  const int wave = tid >> 6;                  // 0..3
  // bijective XCD swizzle: each XCD gets 64 consecutive swz = 2 (col,z) panels
  const int bid = blockIdx.x + 32 * (blockIdx.y + 4 * (int)blockIdx.z);
  const int swz = (bid & 7) * 64 + (bid >> 3);     // 512 blocks, bijective
  const int row0 = (swz & 31) * 128;
  const int byz  = swz >> 5;                       // 0..15
  const int col0 = (byz & 3) * 256;
  const int z    = byz >> 2;
  const int wr = wave >> 1, wc = wave & 1;    // wave tile 64 rows x 128 cols
  const int l15 = lane & 15, l4 = lane >> 4;
  const int arow = tid >> 1, ahalf = tid & 1; // A stage: row, k-half (16 bf16)

  // stage power rows -> Pl (8 floats per thread)
  {
    const int pr = tid >> 1, pj = (tid & 1) * 8;
    float4 pa = *(const float4*)(power + (size_t)(row0 + pr) * 16 + pj);
    float4 pb2 = *(const float4*)(power + (size_t)(row0 + pr) * 16 + pj + 4);
    Pl[pr][pj + 0] = pa.x; Pl[pr][pj + 1] = pa.y;
    Pl[pr][pj + 2] = pa.z; Pl[pr][pj + 3] = pa.w;
    Pl[pr][pj + 4] = pb2.x; Pl[pr][pj + 5] = pb2.y;
    Pl[pr][pj + 6] = pb2.z; Pl[pr][pj + 7] = pb2.w;
  }

  f32x4 acc[4][8];
  #pragma unroll
  for (int m = 0; m < 4; ++m)
    #pragma unroll
    for (int n = 0; n < 8; ++n)
      #pragma unroll
      for (int q = 0; q < 4; ++q) acc[m][n][q] = 0.0f;

  // thread's x slice: row arow, k-half ahalf (16 floats of each 32-chunk)
  const float* xrow = x + (size_t)(row0 + arow) * 1024 + ahalf * 16;
  u16* const blbase = (u16*)Bl2;              // per-buffer stride: 8192 u16
  float xv[16];

  __syncthreads();   // Pl ready

  // prologue: stage t=0 into buf0
  {
    const int kt0 = z * 128;
    const float* xs = xrow + (kt0 >> 4) * 32;
    #pragma unroll
    for (int h = 0; h < 4; ++h) {
      float4 v = *(const float4*)(xs + h * 4);
      xv[h*4+0]=v.x; xv[h*4+1]=v.y; xv[h*4+2]=v.z; xv[h*4+3]=v.w;
    }
    const u16* bsrc = Bp + (size_t)kt0 * 32768;
    #pragma unroll
    for (int q = 0; q < 4; ++q) {
      const int g = wave * 4 + q;
      gload_lds16(bsrc + (g >> 2) * 8192 + (col0 + (g & 3) * 64) * 8 + lane * 8,
                  blbase + g * 512 + lane * 8);
    }
    const float pw = Pl[arow][0];
    float tv[16];
    #pragma unroll
    for (int e = 0; e < 16; ++e) tv[e] = xv[e] * pw;
    *(short8x*)&Al2[0][ahalf * 2][arow][0] = cvt8(tv);
    *(short8x*)&Al2[0][ahalf * 2 + 1][arow][0] = cvt8(tv + 8);
  }
  __syncthreads();

  for (int t = 0; t < 128; ++t) {
    const int cb = t & 1;
    if (t < 127) {                 // stage t+1 into buf cb^1
      const int tn = t + 1, ktn = z * 128 + tn, iin = tn & 15, pb = tn & 1;
      const u16* bsrc = Bp + (size_t)ktn * 32768;
      #pragma unroll
      for (int q = 0; q < 4; ++q) {
        const int g = wave * 4 + q;
        gload_lds16(bsrc + (g >> 2) * 8192 + (col0 + (g & 3) * 64) * 8 + lane * 8,
                    blbase + pb * 8192 + g * 512 + lane * 8);
      }
      if (iin == 0) {              // new kc: reload x chunk (uniform branch)
        const float* xs = xrow + (ktn >> 4) * 32;
        #pragma unroll
        for (int h = 0; h < 4; ++h) {
          float4 v = *(const float4*)(xs + h * 4);
          xv[h*4+0]=v.x; xv[h*4+1]=v.y; xv[h*4+2]=v.z; xv[h*4+3]=v.w;
        }
      }
      const float pw = Pl[arow][iin];
      float tv[16];
      #pragma unroll
      for (int e = 0; e < 16; ++e) tv[e] = xv[e] * pw;
      *(short8x*)&Al2[pb][ahalf * 2][arow][0] = cvt8(tv);
      *(short8x*)&Al2[pb][ahalf * 2 + 1][arow][0] = cvt8(tv + 8);
    }
    // compute t from buf cb (frag reads conflict-free)
    short8x af[4], bf[8];
    #pragma unroll
    for (int m = 0; m < 4; ++m)
      af[m] = *(const short8x*)&Al2[cb][l4][wr * 64 + m * 16 + l15][0];
    #pragma unroll
    for (int n = 0; n < 8; ++n)
      bf[n] = *(const short8x*)&Bl2[cb][l4][wc * 128 + n * 16 + l15][0];
    #pragma unroll
    for (int m = 0; m < 4; ++m)
      #pragma unroll
      for (int n = 0; n < 8; ++n)
        acc[m][n] = __builtin_amdgcn_mfma_f32_16x16x32_bf16(
            af[m], bf[n], acc[m][n], 0, 0, 0);
    __syncthreads();
  }

  if (z == 0) {   // bias fold: A-ext[row][k<16]=power[row][k]; B-ext[k<16][o]=by[k][o]
    {
      float tv[16];
      #pragma unroll
      for (int e = 0; e < 16; ++e)
        tv[e] = (ahalf == 0) ? Pl[arow][e] : 0.0f;
      *(short8x*)&Al2[0][ahalf * 2][arow][0] = cvt8(tv);
      *(short8x*)&Al2[0][ahalf * 2 + 1][arow][0] = cvt8(tv + 8);
    }
    #pragma unroll
    for (int cpass = 0; cpass < 4; ++cpass) {
      const int cell = tid + cpass * 256;
      const int sb = cell >> 8, cl = cell & 255;
      union { short8x s; u16 h[8]; } p;
      #pragma unroll
      for (int r = 0; r < 8; ++r)
        p.h[r] = (sb < 2) ? f2bf(by[(size_t)(sb * 8 + r) * 1024 + col0 + cl])
                          : (u16)0;
      *(short8x*)&Bl2[0][sb][cl][0] = p.s;
    }
    __syncthreads();
    short8x af[4], bf[8];
    #pragma unroll
    for (int m = 0; m < 4; ++m)
      af[m] = *(const short8x*)&Al2[0][l4][wr * 64 + m * 16 + l15][0];
    #pragma unroll
    for (int n = 0; n < 8; ++n)
      bf[n] = *(const short8x*)&Bl2[0][l4][wc * 128 + n * 16 + l15][0];
    #pragma unroll
    for (int m = 0; m < 4; ++m)
      #pragma unroll
      for (int n = 0; n < 8; ++n)
        acc[m][n] = __builtin_amdgcn_mfma_f32_16x16x32_bf16(
            af[m], bf[n], acc[m][n], 0, 0, 0);
  }

  // epilogue: C/D layout col = lane&15, row = (lane>>4)*4 + q
  #pragma unroll
  for (int m = 0; m < 4; ++m) {
    const int rb = row0 + wr * 64 + m * 16 + l4 * 4;
    #pragma unroll
    for (int n = 0; n < 8; ++n) {
      const int cg = col0 + wc * 128 + n * 16 + l15;
      #pragma unroll
      for (int q = 0; q < 4; ++q)
        atomicAdd(out + (size_t)(rb + q) * 1024 + cg, acc[m][n][q]);
    }
  }
}

// ---------------------------------------------------------------------------
extern "C" void kernel_launch(void* const* d_in, const int* in_sizes, int n_in,
                              void* d_out, int out_size, void* d_ws, size_t ws_size,
                              hipStream_t stream) {
  const float* x  = (const float*)d_in[0];
  const float* Wy = (const float*)d_in[1];
  const float* by = (const float*)d_in[2];
  const float* Wd = (const float*)d_in[3];
  const float* bd = (const float*)d_in[4];
  float* out = (float*)d_out;

  char* ws = (char*)d_ws;
  u16*   Bp    = (u16*)ws;                       // 32 MB (bf16 Wy, retiled)
  float* power = (float*)(ws + 33554432);        // 256 KB
  // total ws usage: 33,816,576 bytes (R1-proven footprint)

  hipMemsetAsync(d_out, 0, (size_t)out_size * sizeof(float), stream);
  convert_wy_kernel<<<512, 256, 0, stream>>>(Wy, Bp);
  logits_solve_kernel<<<256, 256, 0, stream>>>(x, Wd, bd, power);
  gemm_kernel<<<dim3(32, 4, 4), 256, 0, stream>>>(x, Bp, power, by, out);
}